// Round 10
// baseline (3653.913 us; speedup 1.0000x reference)
//
#include <hip/hip_runtime.h>

constexpr int B = 32, L = 1024, D = 512, H = 512;

// ---- LDS byte offsets ----
// A tiles: [16 rows][512 k] bf16 (rows 8..15 permanently zero).
constexpr int AH_HI = 0;        // h hi
constexpr int AH_LO = 16384;    // h lo
constexpr int AX_OFF = 32768;   // x single bf16
// B tiles: [2 tiles][16 n][512 k] bf16. BH tile0=[Whz|Whr] tile1=[Whh|0];
// BX tile0=[Wxz|Wxr] tile1=[0|Wxh].
constexpr int BH_OFF = 49152;
constexpr int BX_OFF = 81920;
// C partials: [4 waves][2 tiles][8 m][17] f32
constexpr int CB_OFF = 114688;
constexpr size_t SMEM_BYTES = 119040;   // 116.25 KiB (proven territory)

// ---- workspace (dword offsets) ----
// hrec: [parity(2)][ring(4)][member(64)][64] u32 (hi16|lo16 bf16 of h)
constexpr int HREC_OFF = 0;          // 32768 dw = 128 KiB
constexpr int FLAGS_OFF = 32768;     // [ring(4)][member(64)] stride 32 dw;
                                     // dwords 0..3 of each line = wave flags

typedef __attribute__((ext_vector_type(8))) short short8v;
typedef __attribute__((ext_vector_type(4))) float f32x4;
using ull = unsigned long long;

__device__ __forceinline__ unsigned short f2bf(float f) {   // RNE f32->bf16
    unsigned u = __float_as_uint(f);
    return (unsigned short)((u + 0x7FFFu + ((u >> 16) & 1u)) >> 16);
}
__device__ __forceinline__ float bf2f(unsigned short b) {
    return __uint_as_float((unsigned)b << 16);
}
// XOR-swizzled byte address within a [row][1024B] tile
__device__ __forceinline__ int aswz(int row, int kbyte) {
    return row * 1024 + (kbyte ^ ((row & 7) << 4));
}
__device__ __forceinline__ ull ld_agent64(const ull* p) {
    return __hip_atomic_load(p, __ATOMIC_RELAXED, __HIP_MEMORY_SCOPE_AGENT);
}
__device__ __forceinline__ void st_agent32(unsigned* p, unsigned v) {
    __hip_atomic_store(p, v, __ATOMIC_RELAXED, __HIP_MEMORY_SCOPE_AGENT);
}

__global__ __launch_bounds__(256, 1)
void gru_w4(const float* __restrict__ x, const float* __restrict__ h0,
            const float* __restrict__ Wxz, const float* __restrict__ Whz,
            const float* __restrict__ bz,
            const float* __restrict__ Wxr, const float* __restrict__ Whr,
            const float* __restrict__ br,
            const float* __restrict__ Wxh, const float* __restrict__ Whh,
            const float* __restrict__ bh,
            float* __restrict__ out, unsigned* __restrict__ ws)
{
    extern __shared__ char smem[];

    const int tid = threadIdx.x;
    const int bid = blockIdx.x;
    // XCD-affinity remap (R5, kept): ring g occupies XCD residues {g, g+4}
    const int g  = bid & 3;          // ring: batches g*8 .. g*8+7
    const int fc = bid >> 2;         // member: features fc*8 .. +7
    const int F0 = fc * 8;

    unsigned* hrec  = ws + HREC_OFF;
    unsigned* fring = ws + FLAGS_OFF + g * 64 * 32;   // ring-local flag lines

    // ---- zero all LDS (A pad rows + B zero-blocks must stay zero) ----
    for (int i = tid; i < (int)(SMEM_BYTES / 16); i += 256)
        *(uint4*)(smem + i * 16) = make_uint4(0, 0, 0, 0);
    __syncthreads();

    // ---- one-time weight staging: bf16, swizzled [n][k] fragments ----
    {
        const float* WSET[2][3] = {{Whz, Whr, Whh}, {Wxz, Wxr, Wxh}};
        const int TB[2][3][2] = {{{0,0},{0,8},{1,0}}, {{0,0},{0,8},{1,8}}};
        for (int s = 0; s < 2; ++s) {
            const int bbase = (s == 0) ? BH_OFF : BX_OFF;
            for (int gi = 0; gi < 3; ++gi) {
                const float* W = WSET[s][gi];
                const int tile = TB[s][gi][0], nb = TB[s][gi][1];
                for (int dk = 0; dk < 2; ++dk) {
                    const int k = 2 * tid + dk;
                    const float* src = W + (size_t)k * H + F0;
                    const float4 a = *(const float4*)src;
                    const float4 bq = *(const float4*)(src + 4);
                    const float v[8] = {a.x, a.y, a.z, a.w, bq.x, bq.y, bq.z, bq.w};
#pragma unroll
                    for (int f = 0; f < 8; ++f)
                        *(unsigned short*)(smem + bbase + tile * 16384 +
                                           aswz(nb + f, k * 2)) = f2bf(v[f]);
                }
            }
        }
    }

    // ---- per-thread roles ----
    // x staging: row srow = tid&7 (bank-spread), 16 cols from scol
    const int srow = tid & 7;
    const int scol = (tid >> 3) * 16;
    // h staging: member hm = tid>>2, quarter hq = tid&3 (16 records = 2 rows)
    const int hm = tid >> 2, hq = tid & 3;
    // MFMA: wave w, lane: rc = A-row / B-col, kb = k-block
    const int w    = tid >> 6;
    const int lane = tid & 63;
    const int rc   = lane & 15;
    const int kb   = lane >> 4;
    int offk[4];
#pragma unroll
    for (int ks = 0; ks < 4; ++ks)
        offk[ks] = aswz(rc, (w * 4 + ks) * 64 + kb * 16);
    // epilogue (4-wave): wave w, lanes 0..15 own pair p = w*16+lane
    const int p  = w * 16 + lane;         // valid when lane<16
    const int em = p >> 3, ef = p & 7;    // batch, feature
    float bzv = 0.f, brv = 0.f, bhv = 0.f, hold = 0.f;
    if (lane < 16) {
        bzv = bz[F0 + ef]; brv = br[F0 + ef]; bhv = bh[F0 + ef];
        hold = h0[(g * 8 + em) * H + F0 + ef];
        // publish initial packed record (parity 0) for this wave's pairs
        const unsigned hi = f2bf(hold);
        const unsigned lo = f2bf(hold - bf2f((unsigned short)hi));
        st_agent32(&hrec[((0 * 4 + g) * 64 + fc) * 64 + p], (hi << 16) | lo);
    }
    // per-wave drain, then each wave publishes its own flag = 1
    asm volatile("s_waitcnt vmcnt(0)" ::: "memory");
    if (lane == 0)
        st_agent32(&fring[fc * 32 + w], 1u);

    // prefetch x(0)
    float4 xr[4];
    {
        const float* xp = x + ((size_t)(g * 8 + srow) * L + 0) * D + scol;
#pragma unroll
        for (int c = 0; c < 4; ++c) xr[c] = *(const float4*)(xp + 4 * c);
    }

    for (int t = 0; t < L; ++t) {
        // ---- stage x(t) as single bf16 (hides LDS work before the poll) ----
        {
            float xv[16];
#pragma unroll
            for (int c = 0; c < 4; ++c) {
                xv[4 * c + 0] = xr[c].x; xv[4 * c + 1] = xr[c].y;
                xv[4 * c + 2] = xr[c].z; xv[4 * c + 3] = xr[c].w;
            }
            unsigned wd[8];
#pragma unroll
            for (int j = 0; j < 8; ++j)
                wd[j] = (unsigned)f2bf(xv[2 * j]) |
                        ((unsigned)f2bf(xv[2 * j + 1]) << 16);
            *(uint4*)(smem + AX_OFF + aswz(srow, scol * 2)) =
                make_uint4(wd[0], wd[1], wd[2], wd[3]);
            *(uint4*)(smem + AX_OFF + aswz(srow, scol * 2 + 16)) =
                make_uint4(wd[4], wd[5], wd[6], wd[7]);
        }

        // ---- all-wave poll: lane l watches member l's 4 wave-flags ----
        const unsigned s = (unsigned)(t + 1);
        {
            const ull* fp = (const ull*)(fring + lane * 32);
            for (;;) {
                const ull f01 = ld_agent64(fp);
                const ull f23 = ld_agent64(fp + 1);
                const unsigned a0 = (unsigned)f01, a1 = (unsigned)(f01 >> 32);
                const unsigned a2 = (unsigned)f23, a3 = (unsigned)(f23 >> 32);
                const bool ok = ((a0 - s) <= 1u) && ((a1 - s) <= 1u) &&
                                ((a2 - s) <= 1u) && ((a3 - s) <= 1u);
                if (__all(ok)) break;
                __builtin_amdgcn_s_sleep(1);
            }
        }
        // no sync here: each wave stages only members it has itself verified

        // ---- stage h(t): bulk-load packed records once, bit-unpack to LDS ----
        {
            const ull* rb = (const ull*)&hrec[(((t & 1) * 4 + g) * 64 + hm) * 64] + hq * 8;
            ull qd[8];
#pragma unroll
            for (int i = 0; i < 8; ++i) qd[i] = ld_agent64(rb + i);
#pragma unroll
            for (int rsel = 0; rsel < 2; ++rsel) {
                const int brow = 2 * hq + rsel;
                unsigned v[8];
#pragma unroll
                for (int f = 0; f < 8; ++f) {
                    const ull qq = qd[rsel * 4 + (f >> 1)];
                    v[f] = (f & 1) ? (unsigned)(qq >> 32) : (unsigned)qq;
                }
                uint4 hi4, lo4;
                hi4.x = (v[0] >> 16) | (v[1] & 0xFFFF0000u);
                hi4.y = (v[2] >> 16) | (v[3] & 0xFFFF0000u);
                hi4.z = (v[4] >> 16) | (v[5] & 0xFFFF0000u);
                hi4.w = (v[6] >> 16) | (v[7] & 0xFFFF0000u);
                lo4.x = (v[0] & 0xFFFFu) | (v[1] << 16);
                lo4.y = (v[2] & 0xFFFFu) | (v[3] << 16);
                lo4.z = (v[4] & 0xFFFFu) | (v[5] << 16);
                lo4.w = (v[6] & 0xFFFFu) | (v[7] << 16);
                const int ad = aswz(brow, hm * 16);
                *(uint4*)(smem + AH_HI + ad) = hi4;
                *(uint4*)(smem + AH_LO + ad) = lo4;
            }
        }
        __syncthreads();   // sync A: all staging visible to all waves

        // ---- MFMA: 3 passes (h_hi, h_lo, x) × 2 N-tiles × 4 k-steps ----
        f32x4 acc0 = {0.f, 0.f, 0.f, 0.f}, acc1 = {0.f, 0.f, 0.f, 0.f};
        {
            const char* Ab[3] = {smem + AH_HI, smem + AH_LO, smem + AX_OFF};
            const char* Bb[3] = {smem + BH_OFF, smem + BH_OFF, smem + BX_OFF};
#pragma unroll
            for (int pi = 0; pi < 3; ++pi) {
#pragma unroll
                for (int ks = 0; ks < 4; ++ks) {
                    const short8v a  = *(const short8v*)(Ab[pi] + offk[ks]);
                    const short8v b0 = *(const short8v*)(Bb[pi] + offk[ks]);
                    const short8v b1 = *(const short8v*)(Bb[pi] + 16384 + offk[ks]);
                    acc0 = __builtin_amdgcn_mfma_f32_16x16x32_bf16(a, b0, acc0, 0, 0, 0);
                    acc1 = __builtin_amdgcn_mfma_f32_16x16x32_bf16(a, b1, acc1, 0, 0, 0);
                }
            }
        }
        // write partial C (valid rows 0..7 live in lanes 0..31)
        if (lane < 32) {
            float* cbp = (float*)(smem + CB_OFF) + w * 272;
            const int mb = (lane >> 4) * 4, col = lane & 15;
#pragma unroll
            for (int reg = 0; reg < 4; ++reg) {
                cbp[(mb + reg) * 17 + col]       = acc0[reg];
                cbp[136 + (mb + reg) * 17 + col] = acc1[reg];
            }
        }
        __syncthreads();   // sync B: all CB partials ready; all MFMA done

        // ---- epilogue: 4 waves in parallel, wave w finalizes 16 pairs ----
        float hnv = 0.f;
        if (lane < 16) {
            float zz = 0.f, rr = 0.f, chh = 0.f, cxx = 0.f;
            const float* cb0 = (const float*)(smem + CB_OFF);
#pragma unroll
            for (int ww = 0; ww < 4; ++ww) {
                const float* cw = cb0 + ww * 272 + em * 17;
                zz  += cw[ef];        rr  += cw[8 + ef];
                chh += cw[136 + ef];  cxx += cw[136 + 8 + ef];
            }
            const float z = 1.f / (1.f + __expf(-(zz + bzv)));
            const float r = 1.f / (1.f + __expf(-(rr + brv)));
            const float pre = cxx + r * (chh + bhv);
            const float e = __expf(-2.f * fabsf(pre));
            float th = (1.f - e) / (1.f + e);
            th = (pre < 0.f) ? -th : th;
            hnv = z * hold + (1.f - z) * th;
            hold = hnv;

            const unsigned hi = f2bf(hnv);
            const unsigned lo = f2bf(hnv - bf2f((unsigned short)hi));
            st_agent32(&hrec[((((t + 1) & 1) * 4 + g) * 64 + fc) * 64 + p],
                       (hi << 16) | lo);
        }
        // per-wave drain of this wave's record stores, then its own flag
        asm volatile("s_waitcnt vmcnt(0)" ::: "memory");
        if (lane == 0)
            st_agent32(&fring[fc * 32 + w], s + 1u);

        // out writes off the critical path
        if (lane < 16) {
            out[((size_t)(g * 8 + em) * L + t) * H + F0 + ef] = hnv;
            if (t == L - 1)
                out[(size_t)B * L * H + (size_t)(g * 8 + em) * H + F0 + ef] = hnv;
        }

        // prefetch x(t+1); latency hides under next step's poll
        if (t + 1 < L) {
            const float* xp = x + ((size_t)(g * 8 + srow) * L + (t + 1)) * D + scol;
#pragma unroll
            for (int c = 0; c < 4; ++c) xr[c] = *(const float4*)(xp + 4 * c);
        }
        // AX/AH overwrite hazards for t+1 are covered by sync B (all MFMA of
        // step t complete before any wave passes it) and by the poll's
        // own-member wave flags (record freshness).
    }
}

extern "C" void kernel_launch(void* const* d_in, const int* in_sizes, int n_in,
                              void* d_out, int out_size, void* d_ws, size_t ws_size,
                              hipStream_t stream) {
    const float* x   = (const float*)d_in[0];
    const float* h0  = (const float*)d_in[1];
    const float* Wxz = (const float*)d_in[2];
    const float* Whz = (const float*)d_in[3];
    const float* bz  = (const float*)d_in[4];
    const float* Wxr = (const float*)d_in[5];
    const float* Whr = (const float*)d_in[6];
    const float* br  = (const float*)d_in[7];
    const float* Wxh = (const float*)d_in[8];
    const float* Whh = (const float*)d_in[9];
    const float* bh  = (const float*)d_in[10];
    float* out = (float*)d_out;
    unsigned* ws = (unsigned*)d_ws;

    (void)hipFuncSetAttribute((const void*)gru_w4,
                              hipFuncAttributeMaxDynamicSharedMemorySize,
                              (int)SMEM_BYTES);

    void* args[] = {(void*)&x, (void*)&h0, (void*)&Wxz, (void*)&Whz, (void*)&bz,
                    (void*)&Wxr, (void*)&Whr, (void*)&br, (void*)&Wxh, (void*)&Whh,
                    (void*)&bh, (void*)&out, (void*)&ws};
    hipError_t err = hipLaunchCooperativeKernel((void*)gru_w4, dim3(256),
                                                dim3(256), args,
                                                (unsigned)SMEM_BYTES, stream);
    if (err != hipSuccess) {
        // kernel uses only its own flag barrier; 256 blocks at 1/CU are
        // trivially co-resident, so a plain launch is a safe fallback
        gru_w4<<<dim3(256), dim3(256), SMEM_BYTES, stream>>>(
            x, h0, Wxz, Whz, bz, Wxr, Whr, br, Wxh, Whh, bh, out, ws);
    }
}